// Round 1
// baseline (385.759 us; speedup 1.0000x reference)
//
#include <hip/hip_runtime.h>
#include <math.h>

// Problem constants (from reference): B=16, H=W=28, C=1, KSIZE=5, KNUM=16,
// VALID stride-1 -> OH=OW=24, P=576 patches, F=25 features/patch.
#define BATCH 16
#define H     28
#define W     28
#define KS    5
#define KN    16
#define OHW   24
#define P     576          // OHW*OHW
#define NTHR  192          // 3 waves; 576 q = 3 exact iterations

// out layout: mu_out [16,24,24,16] = 147456 floats, then
//             Sigma  [16,576,576,16] = 84934656 floats.
#define MU_OUT_ELEMS (BATCH * P * KN)

__global__ __launch_bounds__(NTHR) void vdp_fused_kernel(
    const float* __restrict__ mu_in,    // [16,28,28,1]
    const float* __restrict__ w_mu,     // [5,5,1,16]
    const float* __restrict__ w_sigma,  // [16]
    float* __restrict__ out)
{
    __shared__ float mu_s[H * W];   // 784 floats, 3.1 KB
    __shared__ float sp_s[KN];      // softplus(w_sigma)

    const int bid = blockIdx.x;     // [0, 16*576)
    const int b   = bid / P;
    const int p   = bid % P;
    const int tid = threadIdx.x;

    // Stage this batch's 28x28 image in LDS.
    const float* mu_b = mu_in + b * (H * W);
    for (int i = tid; i < H * W; i += NTHR) mu_s[i] = mu_b[i];
    if (tid < KN) sp_s[tid] = log1pf(expf(w_sigma[tid]));
    __syncthreads();

    // Patch p in registers (broadcast LDS reads — wave-uniform address).
    const int ph = p / OHW;
    const int pw = p % OHW;
    float Xp[KS * KS];
    #pragma unroll
    for (int kh = 0; kh < KS; ++kh)
        #pragma unroll
        for (int kw = 0; kw < KS; ++kw)
            Xp[kh * KS + kw] = mu_s[(ph + kh) * W + (pw + kw)];

    // mu_out row for (b, p): first 16 threads each do one output channel.
    // mu_out[b, ph, pw, k] = sum_j Xp[j] * w_mu[j, k]   (w_mu is [5,5,1,16])
    if (tid < KN) {
        float acc = 0.f;
        #pragma unroll
        for (int j = 0; j < KS * KS; ++j)
            acc += Xp[j] * w_mu[j * KN + tid];
        out[(b * P + p) * KN + tid] = acc;
    }

    // Sigma rows: thread handles q = tid, tid+192, tid+384 (576 = 3*192 exact).
    float* sig = out + MU_OUT_ELEMS;
    const int rowbase = (b * P + p) * P * KN;   // max ~84.9M, fits int32

    #pragma unroll
    for (int it = 0; it < 3; ++it) {
        const int q  = tid + it * NTHR;
        const int qh = q / OHW;
        const int qw = q % OHW;
        const float* mq = &mu_s[qh * W + qw];

        float g = 0.f;
        #pragma unroll
        for (int kh = 0; kh < KS; ++kh)
            #pragma unroll
            for (int kw = 0; kw < KS; ++kw)
                g += Xp[kh * KS + kw] * mq[kh * W + kw];

        float v[KN];
        #pragma unroll
        for (int k = 0; k < KN; ++k) {
            float val = sp_s[k] * g;
            // set_diag on last two dims (q, k): abs where q == k (q < 16)
            if (q == k) val = fabsf(val);
            v[k] = val;
        }

        float4* dst = (float4*)(sig + rowbase + q * KN);  // 16B-aligned
        dst[0] = make_float4(v[0],  v[1],  v[2],  v[3]);
        dst[1] = make_float4(v[4],  v[5],  v[6],  v[7]);
        dst[2] = make_float4(v[8],  v[9],  v[10], v[11]);
        dst[3] = make_float4(v[12], v[13], v[14], v[15]);
    }
}

extern "C" void kernel_launch(void* const* d_in, const int* in_sizes, int n_in,
                              void* d_out, int out_size, void* d_ws, size_t ws_size,
                              hipStream_t stream) {
    const float* mu_in   = (const float*)d_in[0];
    const float* w_mu    = (const float*)d_in[1];
    const float* w_sigma = (const float*)d_in[2];
    float* out = (float*)d_out;

    dim3 grid(BATCH * P);   // 9216 blocks
    dim3 block(NTHR);
    vdp_fused_kernel<<<grid, block, 0, stream>>>(mu_in, w_mu, w_sigma, out);
}

// Round 2
// 351.058 us; speedup vs baseline: 1.0988x; 1.0988x over previous
//
#include <hip/hip_runtime.h>
#include <math.h>

// B=16, H=W=28, C=1, KSIZE=5, KNUM=16, VALID stride-1 -> OH=OW=24, P=576.
#define BATCH 16
#define H     28
#define W     28
#define KS    5
#define KN    16
#define OHW   24
#define P     576
#define NTHR  256
#define PPB   4            // p-rows per block
#define MU_OUT_ELEMS (BATCH * P * KN)

__global__ __launch_bounds__(NTHR) void vdp_fused_kernel(
    const float* __restrict__ mu_in,    // [16,28,28,1]
    const float* __restrict__ w_mu,     // [5,5,1,16]
    const float* __restrict__ w_sigma,  // [16]
    float* __restrict__ out)
{
    __shared__ float mu_s[H * W];   // 3.1 KB
    __shared__ float sp_s[KN];
    __shared__ float g_s[P];        // 2.3 KB — Gram row for current p

    const int blocks_per_b = P / PPB;           // 144
    const int b     = blockIdx.x / blocks_per_b;
    const int pbase = (blockIdx.x % blocks_per_b) * PPB;
    const int tid   = threadIdx.x;

    // Stage this batch's 28x28 image + softplus scales.
    const float* mu_b = mu_in + b * (H * W);
    for (int i = tid; i < H * W; i += NTHR) mu_s[i] = mu_b[i];
    if (tid < KN) sp_s[tid] = log1pf(expf(w_sigma[tid]));
    __syncthreads();

    float* sig = out + MU_OUT_ELEMS;

    for (int pi = 0; pi < PPB; ++pi) {
        const int p  = pbase + pi;
        const int ph = p / OHW;
        const int pw = p % OHW;

        // Patch p in registers (block-uniform LDS broadcast reads).
        float Xp[KS * KS];
        #pragma unroll
        for (int kh = 0; kh < KS; ++kh)
            #pragma unroll
            for (int kw = 0; kw < KS; ++kw)
                Xp[kh * KS + kw] = mu_s[(ph + kh) * W + (pw + kw)];

        // mu_out row: first 16 threads each one output channel.
        if (tid < KN) {
            float acc = 0.f;
            #pragma unroll
            for (int j = 0; j < KS * KS; ++j)
                acc += Xp[j] * w_mu[j * KN + tid];
            out[(b * P + p) * KN + tid] = acc;
        }

        // Phase 1: Gram row g[q] = <Xp, Xq> into LDS.
        for (int q = tid; q < P; q += NTHR) {
            const int qh = q / OHW;
            const int qw = q % OHW;
            const float* mq = &mu_s[qh * W + qw];
            float g = 0.f;
            #pragma unroll
            for (int kh = 0; kh < KS; ++kh)
                #pragma unroll
                for (int kw = 0; kw < KS; ++kw)
                    g += Xp[kh * KS + kw] * mq[kh * W + kw];
            g_s[q] = g;
        }
        __syncthreads();

        // Phase 2: fully-coalesced writes. Row = P*KN floats = 2304 float4s
        // = 9 per thread. Flat float4 index f -> q = f>>2, channel group c = f&3.
        float4* rowp = (float4*)(sig + (size_t)(b * P + p) * (P * KN));
        #pragma unroll
        for (int j = 0; j < 9; ++j) {
            const int f = j * NTHR + tid;
            const int q = f >> 2;
            const int c = f & 3;
            const float g = g_s[q];
            float4 v = make_float4(g * sp_s[4 * c + 0], g * sp_s[4 * c + 1],
                                   g * sp_s[4 * c + 2], g * sp_s[4 * c + 3]);
            // set_diag on last two dims (q, channel): abs where channel == q, q < 16
            if (q < KN && (q >> 2) == c) {
                const int r = q & 3;
                if (r == 0) v.x = fabsf(v.x);
                else if (r == 1) v.y = fabsf(v.y);
                else if (r == 2) v.z = fabsf(v.z);
                else v.w = fabsf(v.w);
            }
            rowp[f] = v;
        }
        __syncthreads();   // protect g_s before next p-iteration overwrites it
    }
}

extern "C" void kernel_launch(void* const* d_in, const int* in_sizes, int n_in,
                              void* d_out, int out_size, void* d_ws, size_t ws_size,
                              hipStream_t stream) {
    const float* mu_in   = (const float*)d_in[0];
    const float* w_mu    = (const float*)d_in[1];
    const float* w_sigma = (const float*)d_in[2];
    float* out = (float*)d_out;

    dim3 grid(BATCH * P / PPB);   // 2304 blocks
    dim3 block(NTHR);
    vdp_fused_kernel<<<grid, block, 0, stream>>>(mu_in, w_mu, w_sigma, out);
}

// Round 3
// 344.712 us; speedup vs baseline: 1.1191x; 1.0184x over previous
//
#include <hip/hip_runtime.h>
#include <math.h>

// B=16, H=W=28, C=1, KSIZE=5, KNUM=16, VALID stride-1 -> OH=OW=24, P=576.
#define BATCH 16
#define H     28
#define W     28
#define KS    5
#define KN    16
#define OHW   24
#define P     576           // = 9 * 64 exactly
#define NTHR  256           // 4 waves; one p-row per wave
#define MU_OUT_ELEMS (BATCH * P * KN)

__global__ __launch_bounds__(NTHR) void vdp_fused_kernel(
    const float* __restrict__ mu_in,    // [16,28,28,1]
    const float* __restrict__ w_mu,     // [5,5,1,16]
    const float* __restrict__ w_sigma,  // [16]
    float* __restrict__ out)
{
    __shared__ float mu_s[H * W];       // 3.1 KB
    __shared__ float wmu_s[KS * KS * KN]; // 1.6 KB
    __shared__ float sp_s[KN];

    const int tid  = threadIdx.x;
    const int wave = tid >> 6;
    const int lane = tid & 63;

    const int blocks_per_b = P / 4;     // 144 (4 p-rows per block, 1 per wave)
    const int b = blockIdx.x / blocks_per_b;
    const int p = (blockIdx.x % blocks_per_b) * 4 + wave;

    // Stage image, conv weights, softplus scales. ONE barrier total.
    const float* mu_b = mu_in + b * (H * W);
    for (int i = tid; i < H * W; i += NTHR) mu_s[i] = mu_b[i];
    for (int i = tid; i < KS * KS * KN; i += NTHR) wmu_s[i] = w_mu[i];
    if (tid < KN) sp_s[tid] = log1pf(expf(w_sigma[tid]));
    __syncthreads();

    const int ph = p / OHW;
    const int pw = p % OHW;

    // Patch p (wave-uniform LDS broadcast reads).
    float Xp[KS * KS];
    #pragma unroll
    for (int kh = 0; kh < KS; ++kh)
        #pragma unroll
        for (int kw = 0; kw < KS; ++kw)
            Xp[kh * KS + kw] = mu_s[(ph + kh) * W + (pw + kw)];

    // mu_out row: lanes 0..15, one output channel each.
    if (lane < KN) {
        float acc = 0.f;
        #pragma unroll
        for (int j = 0; j < KS * KS; ++j)
            acc += Xp[j] * wmu_s[j * KN + lane];
        out[(b * P + p) * KN + lane] = acc;
    }

    // Gram row in registers: g[r] = <Xp, X_{q}>, q = 64*r + lane. 576 = 9*64.
    float g[9];
    #pragma unroll
    for (int r = 0; r < 9; ++r) {
        const int q  = r * 64 + lane;
        const int qh = q / OHW;
        const int qw = q % OHW;
        const float* mq = &mu_s[qh * W + qw];
        float acc = 0.f;
        #pragma unroll
        for (int kh = 0; kh < KS; ++kh)
            #pragma unroll
            for (int kw = 0; kw < KS; ++kw)
                acc += Xp[kh * KS + kw] * mq[kh * W + kw];
        g[r] = acc;
    }

    // This lane's 4 channels: c = lane&3 -> channels 4c..4c+3.
    const int c = lane & 3;
    const float sc0 = sp_s[4 * c + 0];
    const float sc1 = sp_s[4 * c + 1];
    const float sc2 = sp_s[4 * c + 2];
    const float sc3 = sp_s[4 * c + 3];

    // Store loop: row = 576*16 floats = 2304 float4 = 36 wave-stores, each a
    // contiguous 1 KB burst. Store s, lane i -> f = 64s+i, q = 16s+(i>>2),
    // computed by lane 16*(s&3)+(i>>2) in g[s>>2]. No barriers — streams.
    float4* rowp = (float4*)(out + MU_OUT_ELEMS + (size_t)(b * P + p) * (P * KN));
    const int src = 16 * 0 + (lane >> 2);   // pattern base; varies with s&3
    #pragma unroll
    for (int s = 0; s < 36; ++s) {
        const float gq = __shfl(g[s >> 2], 16 * (s & 3) + (lane >> 2));
        float4 v = make_float4(gq * sc0, gq * sc1, gq * sc2, gq * sc3);
        if (s == 0) {
            // diag: q = lane>>2 (<16), abs where channel==q -> c==q>>2, comp q&3
            const int q = lane >> 2;
            if ((q >> 2) == c) {
                const int r2 = q & 3;
                if (r2 == 0) v.x = fabsf(v.x);
                else if (r2 == 1) v.y = fabsf(v.y);
                else if (r2 == 2) v.z = fabsf(v.z);
                else v.w = fabsf(v.w);
            }
        }
        rowp[s * 64 + lane] = v;
    }
    (void)src;
}

extern "C" void kernel_launch(void* const* d_in, const int* in_sizes, int n_in,
                              void* d_out, int out_size, void* d_ws, size_t ws_size,
                              hipStream_t stream) {
    const float* mu_in   = (const float*)d_in[0];
    const float* w_mu    = (const float*)d_in[1];
    const float* w_sigma = (const float*)d_in[2];
    float* out = (float*)d_out;

    dim3 grid(BATCH * P / 4);   // 2304 blocks, 1 p-row per wave
    dim3 block(NTHR);
    vdp_fused_kernel<<<grid, block, 0, stream>>>(mu_in, w_mu, w_sigma, out);
}

// Round 5
// 343.331 us; speedup vs baseline: 1.1236x; 1.0040x over previous
//
#include <hip/hip_runtime.h>
#include <math.h>

// B=16, H=W=28, C=1, KSIZE=5, KNUM=16, VALID stride-1 -> OH=OW=24, P=576.
#define BATCH 16
#define H     28
#define W     28
#define KS    5
#define KN    16
#define OHW   24
#define P     576           // = 9 * 64 exactly
#define NTHR  256           // 4 waves; one p-row per wave
#define MU_OUT_ELEMS (BATCH * P * KN)

typedef float vfloat4 __attribute__((ext_vector_type(4)));  // native vec for
// __builtin_nontemporal_store (HIP_vector_type float4 is rejected by the builtin)

__global__ __launch_bounds__(NTHR) void vdp_fused_kernel(
    const float* __restrict__ mu_in,    // [16,28,28,1]
    const float* __restrict__ w_mu,     // [5,5,1,16]
    const float* __restrict__ w_sigma,  // [16]
    float* __restrict__ out)
{
    __shared__ float mu_s[H * W];         // 3.1 KB
    __shared__ float wmu_s[KS * KS * KN]; // 1.6 KB
    __shared__ float sp_s[KN];

    const int tid  = threadIdx.x;
    const int wave = tid >> 6;
    const int lane = tid & 63;

    const int blocks_per_b = P / 4;     // 144 (4 p-rows per block, 1 per wave)
    const int b = blockIdx.x / blocks_per_b;
    const int p = (blockIdx.x % blocks_per_b) * 4 + wave;

    // Stage image, conv weights, softplus scales. ONE barrier total.
    const float* mu_b = mu_in + b * (H * W);
    for (int i = tid; i < H * W; i += NTHR) mu_s[i] = mu_b[i];
    for (int i = tid; i < KS * KS * KN; i += NTHR) wmu_s[i] = w_mu[i];
    if (tid < KN) sp_s[tid] = log1pf(expf(w_sigma[tid]));
    __syncthreads();

    const int ph = p / OHW;
    const int pw = p % OHW;

    // Patch p (wave-uniform LDS broadcast reads).
    float Xp[KS * KS];
    #pragma unroll
    for (int kh = 0; kh < KS; ++kh)
        #pragma unroll
        for (int kw = 0; kw < KS; ++kw)
            Xp[kh * KS + kw] = mu_s[(ph + kh) * W + (pw + kw)];

    // mu_out row: lanes 0..15, one output channel each.
    if (lane < KN) {
        float acc = 0.f;
        #pragma unroll
        for (int j = 0; j < KS * KS; ++j)
            acc += Xp[j] * wmu_s[j * KN + lane];
        out[(b * P + p) * KN + lane] = acc;
    }

    // This lane's 4 channels: c = lane&3 -> channels 4c..4c+3.
    const int c = lane & 3;
    const float sc0 = sp_s[4 * c + 0];
    const float sc1 = sp_s[4 * c + 1];
    const float sc2 = sp_s[4 * c + 2];
    const float sc3 = sp_s[4 * c + 3];

    vfloat4* rowp = (vfloat4*)(out + MU_OUT_ELEMS + (size_t)(b * P + p) * (P * KN));

    // Interleaved compute->store: for each r, compute Gram chunk
    // g = <Xp, X_{64r+lane}>, then immediately emit its 4 contiguous
    // 1 KB wave-stores (s = 4r+t). Stores start after 1/9 of the compute,
    // keeping the store pipe fed for the whole kernel. No barriers.
    #pragma unroll
    for (int r = 0; r < 9; ++r) {
        const int q  = r * 64 + lane;
        const int qh = q / OHW;
        const int qw = q % OHW;
        const float* mq = &mu_s[qh * W + qw];
        float g = 0.f;
        #pragma unroll
        for (int kh = 0; kh < KS; ++kh)
            #pragma unroll
            for (int kw = 0; kw < KS; ++kw)
                g += Xp[kh * KS + kw] * mq[kh * W + kw];

        // Store s = 4r+t, lane i -> float4 index f = 64s+i, row pos
        // q' = 16s+(i>>2), held by lane 16*t + (i>>2) of this chunk.
        #pragma unroll
        for (int t = 0; t < 4; ++t) {
            const int s = 4 * r + t;
            const float gq = __shfl(g, 16 * t + (lane >> 2));
            vfloat4 v = { gq * sc0, gq * sc1, gq * sc2, gq * sc3 };
            if (r == 0 && t == 0) {
                // diag: q' = lane>>2 (<16), abs where channel==q' ->
                // c == q'>>2, component q'&3
                const int qq = lane >> 2;
                if ((qq >> 2) == c) {
                    const int r2 = qq & 3;
                    v[r2] = fabsf(v[r2]);
                }
            }
            __builtin_nontemporal_store(v, &rowp[s * 64 + lane]);
        }
    }
}

extern "C" void kernel_launch(void* const* d_in, const int* in_sizes, int n_in,
                              void* d_out, int out_size, void* d_ws, size_t ws_size,
                              hipStream_t stream) {
    const float* mu_in   = (const float*)d_in[0];
    const float* w_mu    = (const float*)d_in[1];
    const float* w_sigma = (const float*)d_in[2];
    float* out = (float*)d_out;

    dim3 grid(BATCH * P / 4);   // 2304 blocks, 1 p-row per wave
    dim3 block(NTHR);
    vdp_fused_kernel<<<grid, block, 0, stream>>>(mu_in, w_mu, w_sigma, out);
}